// Round 1
// baseline (253.932 us; speedup 1.0000x reference)
//
#include <hip/hip_runtime.h>
#include <math.h>

#define SE_B   32
#define SE_C   256
#define SE_HID 16
#define SE_HW  4096   // 64*64
#define SE_HW4 1024   // float4 per (b,c) plane

typedef float f4v __attribute__((ext_vector_type(4)));

// Kernel 1: per-(b,c) plane mean. One 256-thread block per plane.
// Normal (caching) loads on purpose: leaves x resident in the 256 MiB L3
// so the apply pass can re-read it without HBM traffic.
__global__ __launch_bounds__(256) void se_mean_kernel(const float* __restrict__ x,
                                                      float* __restrict__ s) {
    const int plane = blockIdx.x;  // b*C + c
    const float4* xp = (const float4*)x + (size_t)plane * SE_HW4;
    const int tid = threadIdx.x;

    float sum = 0.f;
#pragma unroll
    for (int k = 0; k < 4; ++k) {
        float4 v = xp[tid + k * 256];
        sum += (v.x + v.y) + (v.z + v.w);
    }
#pragma unroll
    for (int off = 32; off > 0; off >>= 1) sum += __shfl_down(sum, off, 64);

    __shared__ float part[4];
    if ((tid & 63) == 0) part[tid >> 6] = sum;
    __syncthreads();
    if (tid == 0) {
        float tot = (part[0] + part[1]) + (part[2] + part[3]);
        s[plane] = tot * (1.0f / SE_HW);
    }
}

// Kernel 2: gate MLP, ONCE per batch (32 blocks total, not 8192).
// h_i = relu(b1_i + sum_c s[b,c]*w1[i,c]);  g_c = sigmoid(b2_c + sum_i h_i*w2[c,i])
__global__ __launch_bounds__(256) void se_gate_kernel(const float* __restrict__ s,
                                                      const float* __restrict__ w1,
                                                      const float* __restrict__ b1,
                                                      const float* __restrict__ w2,
                                                      const float* __restrict__ b2,
                                                      float* __restrict__ g) {
    const int b = blockIdx.x;      // batch
    const int tid = threadIdx.x;   // also the output channel c

    __shared__ float s_sh[SE_C];
    __shared__ float part[16][17];   // [chunk j][hidden i], +1 col padding
    __shared__ float h_sh[SE_HID];

    s_sh[tid] = s[b * SE_C + tid];
    __syncthreads();

    // Stage 1: partial dot products. thread (i = tid&15 hidden, j = tid>>4 chunk)
    const int i = tid & 15;
    const int j = tid >> 4;
    {
        const float* wrow = w1 + i * SE_C + j * 16;
        const float* srow = s_sh + j * 16;
        float p = 0.f;
#pragma unroll
        for (int k = 0; k < 16; ++k) p = fmaf(srow[k], wrow[k], p);
        part[j][i] = p;
    }
    __syncthreads();

    // Stage 2: column-sum -> h
    if (tid < SE_HID) {
        float acc = b1[tid];
#pragma unroll
        for (int k = 0; k < 16; ++k) acc += part[k][tid];
        h_sh[tid] = fmaxf(acc, 0.f);
    }
    __syncthreads();

    // Stage 3: every thread computes one channel's gate
    {
        float acc = b2[tid];
        const float* w2r = w2 + tid * SE_HID;
#pragma unroll
        for (int k = 0; k < 16; ++k) acc = fmaf(h_sh[k], w2r[k], acc);
        g[b * SE_C + tid] = 1.0f / (1.0f + expf(-acc));
    }
}

// Kernel 3: pure streaming scale. No LDS, no barriers, no divergence.
// g[plane] is block-uniform -> compiler emits a scalar load.
// NT stores keep the 128 MiB of output from evicting x in L3.
__global__ __launch_bounds__(256) void se_apply_kernel(const float* __restrict__ x,
                                                       const float* __restrict__ g,
                                                       float* __restrict__ out) {
    const int plane = blockIdx.x;
    const int tid = threadIdx.x;

    const float gv = g[plane];
    const float4* xp = (const float4*)x + (size_t)plane * SE_HW4;
    float4* op = (float4*)out + (size_t)plane * SE_HW4;

    float4 v0 = xp[tid];
    float4 v1 = xp[tid + 256];
    float4 v2 = xp[tid + 512];
    float4 v3 = xp[tid + 768];

    v0.x *= gv; v0.y *= gv; v0.z *= gv; v0.w *= gv;
    v1.x *= gv; v1.y *= gv; v1.z *= gv; v1.w *= gv;
    v2.x *= gv; v2.y *= gv; v2.z *= gv; v2.w *= gv;
    v3.x *= gv; v3.y *= gv; v3.z *= gv; v3.w *= gv;

    __builtin_nontemporal_store(*(f4v*)&v0, (f4v*)(op + tid));
    __builtin_nontemporal_store(*(f4v*)&v1, (f4v*)(op + tid + 256));
    __builtin_nontemporal_store(*(f4v*)&v2, (f4v*)(op + tid + 512));
    __builtin_nontemporal_store(*(f4v*)&v3, (f4v*)(op + tid + 768));
}

extern "C" void kernel_launch(void* const* d_in, const int* in_sizes, int n_in,
                              void* d_out, int out_size, void* d_ws, size_t ws_size,
                              hipStream_t stream) {
    const float* x  = (const float*)d_in[0];
    const float* w1 = (const float*)d_in[1];
    const float* b1 = (const float*)d_in[2];
    const float* w2 = (const float*)d_in[3];
    const float* b2 = (const float*)d_in[4];
    float* out = (float*)d_out;

    float* s = (float*)d_ws;              // [B*C] plane means
    float* g = (float*)d_ws + SE_B * SE_C; // [B*C] gates

    se_mean_kernel<<<SE_B * SE_C, 256, 0, stream>>>(x, s);
    se_gate_kernel<<<SE_B, 256, 0, stream>>>(s, w1, b1, w2, b2, g);
    se_apply_kernel<<<SE_B * SE_C, 256, 0, stream>>>(x, g, out);
}